// Round 1
// baseline (121.439 us; speedup 1.0000x reference)
//
#include <hip/hip_runtime.h>
#include <math.h>

#define BB 8
#define NN 2048
#define IN_DIM 256
#define OUT_DIM 128
#define M_TOT (BB*NN)          // 16384
#define CHUNK 32
#define NCHUNK (NN/CHUNK)      // 64

// ---------------- workspace layout (in floats) ----------------
static const size_t OFF_H    = 0;                                   // h: M_TOT*128
static const size_t OFF_SRC  = OFF_H   + (size_t)M_TOT*OUT_DIM;     // 16384
static const size_t OFF_DST  = OFF_SRC + M_TOT;
static const size_t OFF_SD   = OFF_DST + M_TOT;                     // sorted_d
static const size_t OFF_SI   = OFF_SD  + M_TOT;                     // sorted_idx (int)
static const size_t OFF_WP   = OFF_SI  + M_TOT;                     // wpos (sorted order)
static const size_t OFF_WN   = OFF_WP  + M_TOT;                     // wneg
static const size_t OFF_CP   = OFF_WN  + M_TOT;                     // chunkPos 8*64*128
static const size_t OFF_CN   = OFF_CP  + (size_t)BB*NCHUNK*OUT_DIM;
static const size_t OFF_CPW  = OFF_CN  + (size_t)BB*NCHUNK*OUT_DIM; // 512
static const size_t OFF_CNW  = OFF_CPW + BB*NCHUNK;
static const size_t OFF_BP   = OFF_CNW + BB*NCHUNK;                 // basePos
static const size_t OFF_BN   = OFF_BP  + (size_t)BB*NCHUNK*OUT_DIM;
static const size_t OFF_BPW  = OFF_BN  + (size_t)BB*NCHUNK*OUT_DIM;
static const size_t OFF_BNW  = OFF_BPW + BB*NCHUNK;
static const size_t OFF_PREH = OFF_BNW + BB*NCHUNK;                 // 8*2049*128
static const size_t OFF_SUFH = OFF_PREH + (size_t)BB*(NN+1)*OUT_DIM;
static const size_t OFF_PREW = OFF_SUFH + (size_t)BB*(NN+1)*OUT_DIM;
static const size_t OFF_SUFW = OFF_PREW + (size_t)BB*(NN+1);
// total ~6.69M floats = ~26.8 MB

// ---------------- Kernel A: h = x @ W^T, plus src/dst dots ----------------
__global__ __launch_bounds__(256) void gat_gemm_kernel(
    const float* __restrict__ x, const float* __restrict__ W,
    const float* __restrict__ a_src, const float* __restrict__ a_dst,
    float* __restrict__ h, float* __restrict__ src, float* __restrict__ dstv)
{
    __shared__ float xs[32][64];     // [k][m]
    __shared__ float wsh[32][128];   // [k][o]
    __shared__ float redS[64][16];
    __shared__ float redD[64][16];
    const int tid = threadIdx.x;
    const int m0 = blockIdx.x * 64;
    const int mt = tid >> 4;   // 0..15 -> 4 rows each
    const int ot = tid & 15;   // 0..15 -> 8 cols each
    float acc[4][8];
#pragma unroll
    for (int i = 0; i < 4; ++i)
#pragma unroll
        for (int j = 0; j < 8; ++j) acc[i][j] = 0.f;

    const float4* x4 = (const float4*)x;
    const float4* W4 = (const float4*)W;

    for (int k0 = 0; k0 < IN_DIM; k0 += 32) {
        // x tile: 64 rows x 32 k  (transposed into xs[k][m])
#pragma unroll
        for (int it = 0; it < 2; ++it) {
            int row = it * 32 + (tid >> 3);
            int c4 = tid & 7;
            float4 v = x4[(size_t)(m0 + row) * (IN_DIM / 4) + (k0 >> 2) + c4];
            xs[c4 * 4 + 0][row] = v.x; xs[c4 * 4 + 1][row] = v.y;
            xs[c4 * 4 + 2][row] = v.z; xs[c4 * 4 + 3][row] = v.w;
        }
        // W tile: 128 o x 32 k (transposed into wsh[k][o])
#pragma unroll
        for (int it = 0; it < 4; ++it) {
            int idx = tid + it * 256;
            int o = idx >> 3;
            int c4 = idx & 7;
            float4 v = W4[(size_t)o * (IN_DIM / 4) + (k0 >> 2) + c4];
            wsh[c4 * 4 + 0][o] = v.x; wsh[c4 * 4 + 1][o] = v.y;
            wsh[c4 * 4 + 2][o] = v.z; wsh[c4 * 4 + 3][o] = v.w;
        }
        __syncthreads();
#pragma unroll
        for (int k = 0; k < 32; ++k) {
            float4 xv = *(const float4*)&xs[k][mt * 4];
            float4 wa = *(const float4*)&wsh[k][ot * 8];
            float4 wb = *(const float4*)&wsh[k][ot * 8 + 4];
            float xm[4] = {xv.x, xv.y, xv.z, xv.w};
            float wv[8] = {wa.x, wa.y, wa.z, wa.w, wb.x, wb.y, wb.z, wb.w};
#pragma unroll
            for (int i = 0; i < 4; ++i)
#pragma unroll
                for (int j = 0; j < 8; ++j)
                    acc[i][j] = fmaf(xm[i], wv[j], acc[i][j]);
        }
        __syncthreads();
    }

    // epilogue: store h tile + partial src/dst dots
    float as8[8], ad8[8];
#pragma unroll
    for (int j = 0; j < 8; ++j) { as8[j] = a_src[ot * 8 + j]; ad8[j] = a_dst[ot * 8 + j]; }
#pragma unroll
    for (int i = 0; i < 4; ++i) {
        int m = m0 + mt * 4 + i;
        float4 v0 = {acc[i][0], acc[i][1], acc[i][2], acc[i][3]};
        float4 v1 = {acc[i][4], acc[i][5], acc[i][6], acc[i][7]};
        ((float4*)h)[(size_t)m * (OUT_DIM / 4) + ot * 2 + 0] = v0;
        ((float4*)h)[(size_t)m * (OUT_DIM / 4) + ot * 2 + 1] = v1;
        float ps = 0.f, pd = 0.f;
#pragma unroll
        for (int j = 0; j < 8; ++j) {
            ps = fmaf(acc[i][j], as8[j], ps);
            pd = fmaf(acc[i][j], ad8[j], pd);
        }
        redS[mt * 4 + i][ot] = ps;
        redD[mt * 4 + i][ot] = pd;
    }
    __syncthreads();
    if (tid < 64) {
        float ss = 0.f, dd = 0.f;
#pragma unroll
        for (int t = 0; t < 16; ++t) { ss += redS[tid][t]; dd += redD[tid][t]; }
        src[m0 + tid] = ss;
        dstv[m0 + tid] = dd;
    }
}

// ---------------- Kernel C: counting-rank sort of dst per batch ----------------
__global__ __launch_bounds__(256) void rank_kernel(
    const float* __restrict__ dstv, const int* __restrict__ mask,
    float* __restrict__ sorted_d, int* __restrict__ sorted_idx,
    float* __restrict__ wpos, float* __restrict__ wneg)
{
    __shared__ float ld[NN];  // 8 KB
    int b  = blockIdx.x >> 3;  // 8 chunks of 256 per batch
    int ch = blockIdx.x & 7;
    const float* db = dstv + b * NN;
    for (int i = threadIdx.x; i < NN; i += 256) ld[i] = db[i];
    __syncthreads();
    int j = ch * 256 + threadIdx.x;
    float myd = ld[j];
    int rank = 0;
#pragma unroll 8
    for (int jj = 0; jj < NN; ++jj) {
        float v = ld[jj];
        rank += (v < myd) || (v == myd && jj < j);
    }
    sorted_d[b * NN + rank]   = myd;
    sorted_idx[b * NN + rank] = j;
    int mk = mask[b * NN + j];
    wpos[b * NN + rank] = mk ? expf(myd) : 0.f;
    wneg[b * NN + rank] = mk ? expf(0.2f * myd) : 0.f;
}

// ---------------- Kernel D1: per-chunk sums ----------------
__global__ __launch_bounds__(128) void chunksum_kernel(
    const float* __restrict__ h, const int* __restrict__ sidx,
    const float* __restrict__ wpos, const float* __restrict__ wneg,
    float* __restrict__ cPos, float* __restrict__ cNeg,
    float* __restrict__ cPosW, float* __restrict__ cNegW)
{
    int b = blockIdx.x / NCHUNK;
    int c = blockIdx.x % NCHUNK;
    int o = threadIdx.x;
    int r0 = c * CHUNK;
    float ap = 0.f, an = 0.f, apw = 0.f, anw = 0.f;
    for (int r = 0; r < CHUNK; ++r) {
        int rr = b * NN + r0 + r;
        int jj = sidx[rr];
        float wp = wpos[rr], wn = wneg[rr];
        float hv = h[((size_t)b * NN + jj) * OUT_DIM + o];
        ap = fmaf(wp, hv, ap);
        an = fmaf(wn, hv, an);
        apw += wp; anw += wn;
    }
    int cidx = b * NCHUNK + c;
    cPos[(size_t)cidx * OUT_DIM + o] = ap;
    cNeg[(size_t)cidx * OUT_DIM + o] = an;
    if (o == 0) { cPosW[cidx] = apw; cNegW[cidx] = anw; }
}

// ---------------- Kernel D2: scan over chunk totals ----------------
__global__ __launch_bounds__(128) void chunkscan_kernel(
    const float* __restrict__ cPos, const float* __restrict__ cNeg,
    const float* __restrict__ cPosW, const float* __restrict__ cNegW,
    float* __restrict__ bPos, float* __restrict__ bNeg,
    float* __restrict__ bPosW, float* __restrict__ bNegW)
{
    int b = blockIdx.x, o = threadIdx.x;
    float acc = 0.f;
    for (int c = 0; c < NCHUNK; ++c) {
        size_t i = (size_t)(b * NCHUNK + c) * OUT_DIM + o;
        bNeg[i] = acc; acc += cNeg[i];
    }
    acc = 0.f;
    for (int c = NCHUNK - 1; c >= 0; --c) {
        size_t i = (size_t)(b * NCHUNK + c) * OUT_DIM + o;
        bPos[i] = acc; acc += cPos[i];
    }
    if (o == 0) {
        float a = 0.f;
        for (int c = 0; c < NCHUNK; ++c) { bNegW[b * NCHUNK + c] = a; a += cNegW[b * NCHUNK + c]; }
        a = 0.f;
        for (int c = NCHUNK - 1; c >= 0; --c) { bPosW[b * NCHUNK + c] = a; a += cPosW[b * NCHUNK + c]; }
    }
}

// ---------------- Kernel D3: expand chunk scan into full prefix/suffix arrays ----------------
__global__ __launch_bounds__(128) void scanwrite_kernel(
    const float* __restrict__ h, const int* __restrict__ sidx,
    const float* __restrict__ wpos, const float* __restrict__ wneg,
    const float* __restrict__ bPos, const float* __restrict__ bNeg,
    const float* __restrict__ bPosW, const float* __restrict__ bNegW,
    float* __restrict__ PreH, float* __restrict__ SufH,
    float* __restrict__ PreW, float* __restrict__ SufW)
{
    int b = blockIdx.x / NCHUNK;
    int c = blockIdx.x % NCHUNK;
    int o = threadIdx.x;
    int r0 = c * CHUNK;
    size_t hb = (size_t)b * NN;
    size_t pb = (size_t)b * (NN + 1);
    int cidx = b * NCHUNK + c;

    // forward (exclusive prefix of wneg*h)
    float acc = bNeg[(size_t)cidx * OUT_DIM + o];
    for (int r = 0; r < CHUNK; ++r) {
        int rr = b * NN + r0 + r;
        PreH[(pb + r0 + r) * OUT_DIM + o] = acc;
        int jj = sidx[rr];
        acc = fmaf(wneg[rr], h[(hb + jj) * OUT_DIM + o], acc);
    }
    if (c == NCHUNK - 1) PreH[(pb + NN) * OUT_DIM + o] = acc;

    // backward (inclusive suffix of wpos*h)
    float accp = bPos[(size_t)cidx * OUT_DIM + o];
    for (int r = CHUNK - 1; r >= 0; --r) {
        int rr = b * NN + r0 + r;
        int jj = sidx[rr];
        accp = fmaf(wpos[rr], h[(hb + jj) * OUT_DIM + o], accp);
        SufH[(pb + r0 + r) * OUT_DIM + o] = accp;
    }
    if (c == NCHUNK - 1) SufH[(pb + NN) * OUT_DIM + o] = 0.f;

    // scalar weight scans
    if (o == 0) {
        float a = bNegW[cidx];
        for (int r = 0; r < CHUNK; ++r) { PreW[pb + r0 + r] = a; a += wneg[b * NN + r0 + r]; }
        if (c == NCHUNK - 1) PreW[pb + NN] = a;
        float ap = bPosW[cidx];
        for (int r = CHUNK - 1; r >= 0; --r) { ap += wpos[b * NN + r0 + r]; SufW[pb + r0 + r] = ap; }
        if (c == NCHUNK - 1) SufW[pb + NN] = 0.f;
    }
}

// ---------------- Kernel E: per-query combine ----------------
__global__ __launch_bounds__(128) void query_kernel(
    const float* __restrict__ src, const float* __restrict__ sorted_d,
    const float* __restrict__ PreH, const float* __restrict__ SufH,
    const float* __restrict__ PreW, const float* __restrict__ SufW,
    float* __restrict__ out)
{
    int q = blockIdx.x;
    int b = q >> 11;
    float s = src[q];
    float t = -s;
    const float* sd = sorted_d + b * NN;
    int lo = 0, hi = NN;
    while (lo < hi) {
        int mid = (lo + hi) >> 1;
        if (sd[mid] > t) hi = mid; else lo = mid + 1;
    }
    size_t base = (size_t)b * (NN + 1) + lo;
    float pe = expf(s), pn = expf(0.2f * s);
    float den = pe * SufW[base] + pn * PreW[base];
    float num = pe * SufH[base * OUT_DIM + threadIdx.x] + pn * PreH[base * OUT_DIM + threadIdx.x];
    out[(size_t)q * OUT_DIM + threadIdx.x] = (den > 0.f) ? num / den : 0.f;
}

// ---------------- launcher ----------------
extern "C" void kernel_launch(void* const* d_in, const int* in_sizes, int n_in,
                              void* d_out, int out_size, void* d_ws, size_t ws_size,
                              hipStream_t stream)
{
    const float* x     = (const float*)d_in[0];
    const int*   mask  = (const int*)d_in[1];
    const float* W     = (const float*)d_in[2];
    const float* a_src = (const float*)d_in[3];
    const float* a_dst = (const float*)d_in[4];
    float* out = (float*)d_out;
    float* ws  = (float*)d_ws;

    float* h        = ws + OFF_H;
    float* src      = ws + OFF_SRC;
    float* dstv     = ws + OFF_DST;
    float* sorted_d = ws + OFF_SD;
    int*   sidx     = (int*)(ws + OFF_SI);
    float* wpos     = ws + OFF_WP;
    float* wneg     = ws + OFF_WN;
    float* cPos     = ws + OFF_CP;
    float* cNeg     = ws + OFF_CN;
    float* cPosW    = ws + OFF_CPW;
    float* cNegW    = ws + OFF_CNW;
    float* bPos     = ws + OFF_BP;
    float* bNeg     = ws + OFF_BN;
    float* bPosW    = ws + OFF_BPW;
    float* bNegW    = ws + OFF_BNW;
    float* PreH     = ws + OFF_PREH;
    float* SufH     = ws + OFF_SUFH;
    float* PreW     = ws + OFF_PREW;
    float* SufW     = ws + OFF_SUFW;

    gat_gemm_kernel<<<M_TOT / 64, 256, 0, stream>>>(x, W, a_src, a_dst, h, src, dstv);
    rank_kernel<<<BB * 8, 256, 0, stream>>>(dstv, mask, sorted_d, sidx, wpos, wneg);
    chunksum_kernel<<<BB * NCHUNK, 128, 0, stream>>>(h, sidx, wpos, wneg, cPos, cNeg, cPosW, cNegW);
    chunkscan_kernel<<<BB, 128, 0, stream>>>(cPos, cNeg, cPosW, cNegW, bPos, bNeg, bPosW, bNegW);
    scanwrite_kernel<<<BB * NCHUNK, 128, 0, stream>>>(h, sidx, wpos, wneg, bPos, bNeg, bPosW, bNegW,
                                                      PreH, SufH, PreW, SufW);
    query_kernel<<<M_TOT, 128, 0, stream>>>(src, sorted_d, PreH, SufH, PreW, SufW, out);
}

// Round 2
// 81.092 us; speedup vs baseline: 1.4975x; 1.4975x over previous
//
#include <hip/hip_runtime.h>
#include <math.h>

#define BB 8
#define NN 2048
#define IN_DIM 256
#define OUT_DIM 128
#define M_TOT (BB*NN)          // 16384
#define CHUNK 32
#define NCHUNK (NN/CHUNK)      // 64

// ---------------- workspace layout (in floats) ----------------
static const size_t OFF_H    = 0;                                   // h: M_TOT*128
static const size_t OFF_SRC  = OFF_H   + (size_t)M_TOT*OUT_DIM;     // 16384
static const size_t OFF_DST  = OFF_SRC + M_TOT;
static const size_t OFF_SD   = OFF_DST + M_TOT;                     // sorted_d
static const size_t OFF_SI   = OFF_SD  + M_TOT;                     // sorted_idx (int)
static const size_t OFF_WP   = OFF_SI  + M_TOT;                     // wpos (sorted order)
static const size_t OFF_WN   = OFF_WP  + M_TOT;                     // wneg
static const size_t OFF_CP   = OFF_WN  + M_TOT;                     // chunkPos 8*64*128
static const size_t OFF_CN   = OFF_CP  + (size_t)BB*NCHUNK*OUT_DIM;
static const size_t OFF_CPW  = OFF_CN  + (size_t)BB*NCHUNK*OUT_DIM; // 512
static const size_t OFF_CNW  = OFF_CPW + BB*NCHUNK;
static const size_t OFF_BP   = OFF_CNW + BB*NCHUNK;                 // basePos
static const size_t OFF_BN   = OFF_BP  + (size_t)BB*NCHUNK*OUT_DIM;
static const size_t OFF_BPW  = OFF_BN  + (size_t)BB*NCHUNK*OUT_DIM;
static const size_t OFF_BNW  = OFF_BPW + BB*NCHUNK;
static const size_t OFF_PREH = OFF_BNW + BB*NCHUNK;                 // 8*2049*128
static const size_t OFF_SUFH = OFF_PREH + (size_t)BB*(NN+1)*OUT_DIM;
static const size_t OFF_PREW = OFF_SUFH + (size_t)BB*(NN+1)*OUT_DIM;
static const size_t OFF_SUFW = OFF_PREW + (size_t)BB*(NN+1);
static const size_t OFF_RP   = OFF_SUFW + (size_t)BB*(NN+1);        // rank partials: M_TOT*8 ints
// total ~6.82M floats = ~27.3 MB

// ---------------- Kernel A: h = x @ W^T, plus src/dst dots ----------------
__global__ __launch_bounds__(256) void gat_gemm_kernel(
    const float* __restrict__ x, const float* __restrict__ W,
    const float* __restrict__ a_src, const float* __restrict__ a_dst,
    float* __restrict__ h, float* __restrict__ src, float* __restrict__ dstv)
{
    __shared__ float xs[32][64];     // [k][m]
    __shared__ float wsh[32][128];   // [k][o]
    __shared__ float redS[64][16];
    __shared__ float redD[64][16];
    const int tid = threadIdx.x;
    const int m0 = blockIdx.x * 64;
    const int mt = tid >> 4;   // 0..15 -> 4 rows each
    const int ot = tid & 15;   // 0..15 -> 8 cols each
    float acc[4][8];
#pragma unroll
    for (int i = 0; i < 4; ++i)
#pragma unroll
        for (int j = 0; j < 8; ++j) acc[i][j] = 0.f;

    const float4* x4 = (const float4*)x;
    const float4* W4 = (const float4*)W;

    for (int k0 = 0; k0 < IN_DIM; k0 += 32) {
        // x tile: 64 rows x 32 k  (transposed into xs[k][m])
#pragma unroll
        for (int it = 0; it < 2; ++it) {
            int row = it * 32 + (tid >> 3);
            int c4 = tid & 7;
            float4 v = x4[(size_t)(m0 + row) * (IN_DIM / 4) + (k0 >> 2) + c4];
            xs[c4 * 4 + 0][row] = v.x; xs[c4 * 4 + 1][row] = v.y;
            xs[c4 * 4 + 2][row] = v.z; xs[c4 * 4 + 3][row] = v.w;
        }
        // W tile: 128 o x 32 k (transposed into wsh[k][o])
#pragma unroll
        for (int it = 0; it < 4; ++it) {
            int idx = tid + it * 256;
            int o = idx >> 3;
            int c4 = idx & 7;
            float4 v = W4[(size_t)o * (IN_DIM / 4) + (k0 >> 2) + c4];
            wsh[c4 * 4 + 0][o] = v.x; wsh[c4 * 4 + 1][o] = v.y;
            wsh[c4 * 4 + 2][o] = v.z; wsh[c4 * 4 + 3][o] = v.w;
        }
        __syncthreads();
#pragma unroll
        for (int k = 0; k < 32; ++k) {
            float4 xv = *(const float4*)&xs[k][mt * 4];
            float4 wa = *(const float4*)&wsh[k][ot * 8];
            float4 wb = *(const float4*)&wsh[k][ot * 8 + 4];
            float xm[4] = {xv.x, xv.y, xv.z, xv.w};
            float wv[8] = {wa.x, wa.y, wa.z, wa.w, wb.x, wb.y, wb.z, wb.w};
#pragma unroll
            for (int i = 0; i < 4; ++i)
#pragma unroll
                for (int j = 0; j < 8; ++j)
                    acc[i][j] = fmaf(xm[i], wv[j], acc[i][j]);
        }
        __syncthreads();
    }

    // epilogue: store h tile + partial src/dst dots
    float as8[8], ad8[8];
#pragma unroll
    for (int j = 0; j < 8; ++j) { as8[j] = a_src[ot * 8 + j]; ad8[j] = a_dst[ot * 8 + j]; }
#pragma unroll
    for (int i = 0; i < 4; ++i) {
        int m = m0 + mt * 4 + i;
        float4 v0 = {acc[i][0], acc[i][1], acc[i][2], acc[i][3]};
        float4 v1 = {acc[i][4], acc[i][5], acc[i][6], acc[i][7]};
        ((float4*)h)[(size_t)m * (OUT_DIM / 4) + ot * 2 + 0] = v0;
        ((float4*)h)[(size_t)m * (OUT_DIM / 4) + ot * 2 + 1] = v1;
        float ps = 0.f, pd = 0.f;
#pragma unroll
        for (int j = 0; j < 8; ++j) {
            ps = fmaf(acc[i][j], as8[j], ps);
            pd = fmaf(acc[i][j], ad8[j], pd);
        }
        redS[mt * 4 + i][ot] = ps;
        redD[mt * 4 + i][ot] = pd;
    }
    __syncthreads();
    if (tid < 64) {
        float ss = 0.f, dd = 0.f;
#pragma unroll
        for (int t = 0; t < 16; ++t) { ss += redS[tid][t]; dd += redD[tid][t]; }
        src[m0 + tid] = ss;
        dstv[m0 + tid] = dd;
    }
}

// ---------------- Kernel R1: partial ranks (jj-chunked) ----------------
// grid = BB * 8 (j-chunks of 256) * 8 (jj-chunks of 256) = 512 blocks
__global__ __launch_bounds__(256) void rankpart_kernel(
    const float* __restrict__ dstv, int* __restrict__ rpart)
{
    __shared__ float ld[256];
    int blk = blockIdx.x;
    int b  = blk >> 6;          // 64 blocks per batch
    int jc = (blk >> 3) & 7;    // j-chunk
    int kc = blk & 7;           // jj-chunk
    const float* db = dstv + b * NN;
    ld[threadIdx.x] = db[kc * 256 + threadIdx.x];
    __syncthreads();
    int j = jc * 256 + threadIdx.x;
    float myd = db[j];
    int base = kc * 256;
    int rank = 0;
    const float4* l4 = (const float4*)ld;
#pragma unroll 8
    for (int q = 0; q < 64; ++q) {
        float4 v = l4[q];
        int jj = base + q * 4;
        rank += (v.x < myd) || (v.x == myd && jj + 0 < j);
        rank += (v.y < myd) || (v.y == myd && jj + 1 < j);
        rank += (v.z < myd) || (v.z == myd && jj + 2 < j);
        rank += (v.w < myd) || (v.w == myd && jj + 3 < j);
    }
    rpart[((size_t)b * NN + j) * 8 + kc] = rank;
}

// ---------------- Kernel R2: combine partials, scatter + weights ----------------
__global__ __launch_bounds__(256) void rankcombine_kernel(
    const float* __restrict__ dstv, const int* __restrict__ mask,
    const int* __restrict__ rpart,
    float* __restrict__ sorted_d, int* __restrict__ sorted_idx,
    float* __restrict__ wpos, float* __restrict__ wneg)
{
    int j = blockIdx.x * 256 + threadIdx.x;   // global 0..16383
    int b = j >> 11;
    const int4* rp = (const int4*)(rpart + (size_t)j * 8);
    int4 r0 = rp[0], r1 = rp[1];
    int rank = r0.x + r0.y + r0.z + r0.w + r1.x + r1.y + r1.z + r1.w;
    float myd = dstv[j];
    int lj = j & (NN - 1);
    sorted_d[b * NN + rank]   = myd;
    sorted_idx[b * NN + rank] = lj;
    int mk = mask[j];
    wpos[b * NN + rank] = mk ? expf(myd) : 0.f;
    wneg[b * NN + rank] = mk ? expf(0.2f * myd) : 0.f;
}

// ---------------- Kernel D1: per-chunk sums ----------------
__global__ __launch_bounds__(128) void chunksum_kernel(
    const float* __restrict__ h, const int* __restrict__ sidx,
    const float* __restrict__ wpos, const float* __restrict__ wneg,
    float* __restrict__ cPos, float* __restrict__ cNeg,
    float* __restrict__ cPosW, float* __restrict__ cNegW)
{
    int b = blockIdx.x / NCHUNK;
    int c = blockIdx.x % NCHUNK;
    int o = threadIdx.x;
    int r0 = c * CHUNK;
    float ap = 0.f, an = 0.f, apw = 0.f, anw = 0.f;
    for (int r = 0; r < CHUNK; ++r) {
        int rr = b * NN + r0 + r;
        int jj = sidx[rr];
        float wp = wpos[rr], wn = wneg[rr];
        float hv = h[((size_t)b * NN + jj) * OUT_DIM + o];
        ap = fmaf(wp, hv, ap);
        an = fmaf(wn, hv, an);
        apw += wp; anw += wn;
    }
    int cidx = b * NCHUNK + c;
    cPos[(size_t)cidx * OUT_DIM + o] = ap;
    cNeg[(size_t)cidx * OUT_DIM + o] = an;
    if (o == 0) { cPosW[cidx] = apw; cNegW[cidx] = anw; }
}

// ---------------- Kernel D2: scan over chunk totals ----------------
__global__ __launch_bounds__(128) void chunkscan_kernel(
    const float* __restrict__ cPos, const float* __restrict__ cNeg,
    const float* __restrict__ cPosW, const float* __restrict__ cNegW,
    float* __restrict__ bPos, float* __restrict__ bNeg,
    float* __restrict__ bPosW, float* __restrict__ bNegW)
{
    int b = blockIdx.x, o = threadIdx.x;
    float acc = 0.f;
    for (int c = 0; c < NCHUNK; ++c) {
        size_t i = (size_t)(b * NCHUNK + c) * OUT_DIM + o;
        bNeg[i] = acc; acc += cNeg[i];
    }
    acc = 0.f;
    for (int c = NCHUNK - 1; c >= 0; --c) {
        size_t i = (size_t)(b * NCHUNK + c) * OUT_DIM + o;
        bPos[i] = acc; acc += cPos[i];
    }
    if (o == 0) {
        float a = 0.f;
        for (int c = 0; c < NCHUNK; ++c) { bNegW[b * NCHUNK + c] = a; a += cNegW[b * NCHUNK + c]; }
        a = 0.f;
        for (int c = NCHUNK - 1; c >= 0; --c) { bPosW[b * NCHUNK + c] = a; a += cPosW[b * NCHUNK + c]; }
    }
}

// ---------------- Kernel D3: expand chunk scan into full prefix/suffix arrays ----------------
__global__ __launch_bounds__(128) void scanwrite_kernel(
    const float* __restrict__ h, const int* __restrict__ sidx,
    const float* __restrict__ wpos, const float* __restrict__ wneg,
    const float* __restrict__ bPos, const float* __restrict__ bNeg,
    const float* __restrict__ bPosW, const float* __restrict__ bNegW,
    float* __restrict__ PreH, float* __restrict__ SufH,
    float* __restrict__ PreW, float* __restrict__ SufW)
{
    int b = blockIdx.x / NCHUNK;
    int c = blockIdx.x % NCHUNK;
    int o = threadIdx.x;
    int r0 = c * CHUNK;
    size_t hb = (size_t)b * NN;
    size_t pb = (size_t)b * (NN + 1);
    int cidx = b * NCHUNK + c;

    // forward (exclusive prefix of wneg*h)
    float acc = bNeg[(size_t)cidx * OUT_DIM + o];
    for (int r = 0; r < CHUNK; ++r) {
        int rr = b * NN + r0 + r;
        PreH[(pb + r0 + r) * OUT_DIM + o] = acc;
        int jj = sidx[rr];
        acc = fmaf(wneg[rr], h[(hb + jj) * OUT_DIM + o], acc);
    }
    if (c == NCHUNK - 1) PreH[(pb + NN) * OUT_DIM + o] = acc;

    // backward (inclusive suffix of wpos*h)
    float accp = bPos[(size_t)cidx * OUT_DIM + o];
    for (int r = CHUNK - 1; r >= 0; --r) {
        int rr = b * NN + r0 + r;
        int jj = sidx[rr];
        accp = fmaf(wpos[rr], h[(hb + jj) * OUT_DIM + o], accp);
        SufH[(pb + r0 + r) * OUT_DIM + o] = accp;
    }
    if (c == NCHUNK - 1) SufH[(pb + NN) * OUT_DIM + o] = 0.f;

    // scalar weight scans
    if (o == 0) {
        float a = bNegW[cidx];
        for (int r = 0; r < CHUNK; ++r) { PreW[pb + r0 + r] = a; a += wneg[b * NN + r0 + r]; }
        if (c == NCHUNK - 1) PreW[pb + NN] = a;
        float ap = bPosW[cidx];
        for (int r = CHUNK - 1; r >= 0; --r) { ap += wpos[b * NN + r0 + r]; SufW[pb + r0 + r] = ap; }
        if (c == NCHUNK - 1) SufW[pb + NN] = 0.f;
    }
}

// ---------------- Kernel E: per-query combine ----------------
__global__ __launch_bounds__(128) void query_kernel(
    const float* __restrict__ src, const float* __restrict__ sorted_d,
    const float* __restrict__ PreH, const float* __restrict__ SufH,
    const float* __restrict__ PreW, const float* __restrict__ SufW,
    float* __restrict__ out)
{
    int q = blockIdx.x;
    int b = q >> 11;
    float s = src[q];
    float t = -s;
    const float* sd = sorted_d + b * NN;
    int lo = 0, hi = NN;
    while (lo < hi) {
        int mid = (lo + hi) >> 1;
        if (sd[mid] > t) hi = mid; else lo = mid + 1;
    }
    size_t base = (size_t)b * (NN + 1) + lo;
    float pe = expf(s), pn = expf(0.2f * s);
    float den = pe * SufW[base] + pn * PreW[base];
    float num = pe * SufH[base * OUT_DIM + threadIdx.x] + pn * PreH[base * OUT_DIM + threadIdx.x];
    out[(size_t)q * OUT_DIM + threadIdx.x] = (den > 0.f) ? num / den : 0.f;
}

// ---------------- launcher ----------------
extern "C" void kernel_launch(void* const* d_in, const int* in_sizes, int n_in,
                              void* d_out, int out_size, void* d_ws, size_t ws_size,
                              hipStream_t stream)
{
    const float* x     = (const float*)d_in[0];
    const int*   mask  = (const int*)d_in[1];
    const float* W     = (const float*)d_in[2];
    const float* a_src = (const float*)d_in[3];
    const float* a_dst = (const float*)d_in[4];
    float* out = (float*)d_out;
    float* ws  = (float*)d_ws;

    float* h        = ws + OFF_H;
    float* src      = ws + OFF_SRC;
    float* dstv     = ws + OFF_DST;
    float* sorted_d = ws + OFF_SD;
    int*   sidx     = (int*)(ws + OFF_SI);
    float* wpos     = ws + OFF_WP;
    float* wneg     = ws + OFF_WN;
    float* cPos     = ws + OFF_CP;
    float* cNeg     = ws + OFF_CN;
    float* cPosW    = ws + OFF_CPW;
    float* cNegW    = ws + OFF_CNW;
    float* bPos     = ws + OFF_BP;
    float* bNeg     = ws + OFF_BN;
    float* bPosW    = ws + OFF_BPW;
    float* bNegW    = ws + OFF_BNW;
    float* PreH     = ws + OFF_PREH;
    float* SufH     = ws + OFF_SUFH;
    float* PreW     = ws + OFF_PREW;
    float* SufW     = ws + OFF_SUFW;
    int*   rpart    = (int*)(ws + OFF_RP);

    gat_gemm_kernel<<<M_TOT / 64, 256, 0, stream>>>(x, W, a_src, a_dst, h, src, dstv);
    rankpart_kernel<<<BB * 64, 256, 0, stream>>>(dstv, rpart);
    rankcombine_kernel<<<M_TOT / 256, 256, 0, stream>>>(dstv, mask, rpart, sorted_d, sidx, wpos, wneg);
    chunksum_kernel<<<BB * NCHUNK, 128, 0, stream>>>(h, sidx, wpos, wneg, cPos, cNeg, cPosW, cNegW);
    chunkscan_kernel<<<BB, 128, 0, stream>>>(cPos, cNeg, cPosW, cNegW, bPos, bNeg, bPosW, bNegW);
    scanwrite_kernel<<<BB * NCHUNK, 128, 0, stream>>>(h, sidx, wpos, wneg, bPos, bNeg, bPosW, bNegW,
                                                      PreH, SufH, PreW, SufW);
    query_kernel<<<M_TOT, 128, 0, stream>>>(src, sorted_d, PreH, SufH, PreW, SufW, out);
}

// Round 3
// 74.920 us; speedup vs baseline: 1.6209x; 1.0824x over previous
//
#include <hip/hip_runtime.h>
#include <math.h>

#define BB 8
#define NN 2048
#define IN_DIM 256
#define OUT_DIM 128
#define M_TOT (BB*NN)          // 16384
#define CHUNK 32
#define NCHUNK (NN/CHUNK)      // 64

// ---------------- workspace layout (in floats) ----------------
static const size_t OFF_H    = 0;                                   // h: M_TOT*128
static const size_t OFF_SRC  = OFF_H   + (size_t)M_TOT*OUT_DIM;     // 16384
static const size_t OFF_DST  = OFF_SRC + M_TOT;
static const size_t OFF_SD   = OFF_DST + M_TOT;                     // sorted_d
static const size_t OFF_SI   = OFF_SD  + M_TOT;                     // sorted_idx (int)
static const size_t OFF_WP   = OFF_SI  + M_TOT;                     // wpos (sorted order)
static const size_t OFF_WN   = OFF_WP  + M_TOT;                     // wneg
static const size_t OFF_CP   = OFF_WN  + M_TOT;                     // chunkPos 8*64*128
static const size_t OFF_CN   = OFF_CP  + (size_t)BB*NCHUNK*OUT_DIM;
static const size_t OFF_CPW  = OFF_CN  + (size_t)BB*NCHUNK*OUT_DIM; // 512
static const size_t OFF_CNW  = OFF_CPW + BB*NCHUNK;
static const size_t OFF_PREH = OFF_CNW + BB*NCHUNK;                 // 8*2049*128
static const size_t OFF_SUFH = OFF_PREH + (size_t)BB*(NN+1)*OUT_DIM;
static const size_t OFF_PREW = OFF_SUFH + (size_t)BB*(NN+1)*OUT_DIM;
static const size_t OFF_SUFW = OFF_PREW + (size_t)BB*(NN+1);
static const size_t OFF_RP   = OFF_SUFW + (size_t)BB*(NN+1);        // rank partials: M_TOT*8 ints

// ---------------- Kernel A: h = x @ W^T, plus src/dst dots ----------------
__global__ __launch_bounds__(256) void gat_gemm_kernel(
    const float* __restrict__ x, const float* __restrict__ W,
    const float* __restrict__ a_src, const float* __restrict__ a_dst,
    float* __restrict__ h, float* __restrict__ src, float* __restrict__ dstv)
{
    __shared__ float xs[32][68];     // [k][m], padded: staging writes 8-way -> 2-way
    __shared__ float wsh[32][132];   // [k][o], padded
    __shared__ float redS[64][16];
    __shared__ float redD[64][16];
    const int tid = threadIdx.x;
    const int m0 = blockIdx.x * 64;
    const int mt = tid >> 4;   // 0..15 -> 4 rows each
    const int ot = tid & 15;   // 0..15 -> 8 cols each
    float acc[4][8];
#pragma unroll
    for (int i = 0; i < 4; ++i)
#pragma unroll
        for (int j = 0; j < 8; ++j) acc[i][j] = 0.f;

    const float4* x4 = (const float4*)x;
    const float4* W4 = (const float4*)W;

    for (int k0 = 0; k0 < IN_DIM; k0 += 32) {
        // x tile: 64 rows x 32 k  (transposed into xs[k][m])
#pragma unroll
        for (int it = 0; it < 2; ++it) {
            int row = it * 32 + (tid >> 3);
            int c4 = tid & 7;
            float4 v = x4[(size_t)(m0 + row) * (IN_DIM / 4) + (k0 >> 2) + c4];
            xs[c4 * 4 + 0][row] = v.x; xs[c4 * 4 + 1][row] = v.y;
            xs[c4 * 4 + 2][row] = v.z; xs[c4 * 4 + 3][row] = v.w;
        }
        // W tile: 128 o x 32 k (transposed into wsh[k][o])
#pragma unroll
        for (int it = 0; it < 4; ++it) {
            int idx = tid + it * 256;
            int o = idx >> 3;
            int c4 = idx & 7;
            float4 v = W4[(size_t)o * (IN_DIM / 4) + (k0 >> 2) + c4];
            wsh[c4 * 4 + 0][o] = v.x; wsh[c4 * 4 + 1][o] = v.y;
            wsh[c4 * 4 + 2][o] = v.z; wsh[c4 * 4 + 3][o] = v.w;
        }
        __syncthreads();
#pragma unroll
        for (int k = 0; k < 32; ++k) {
            float4 xv = *(const float4*)&xs[k][mt * 4];
            float4 wa = *(const float4*)&wsh[k][ot * 8];
            float4 wb = *(const float4*)&wsh[k][ot * 8 + 4];
            float xm[4] = {xv.x, xv.y, xv.z, xv.w};
            float wv[8] = {wa.x, wa.y, wa.z, wa.w, wb.x, wb.y, wb.z, wb.w};
#pragma unroll
            for (int i = 0; i < 4; ++i)
#pragma unroll
                for (int j = 0; j < 8; ++j)
                    acc[i][j] = fmaf(xm[i], wv[j], acc[i][j]);
        }
        __syncthreads();
    }

    // epilogue: store h tile + partial src/dst dots
    float as8[8], ad8[8];
#pragma unroll
    for (int j = 0; j < 8; ++j) { as8[j] = a_src[ot * 8 + j]; ad8[j] = a_dst[ot * 8 + j]; }
#pragma unroll
    for (int i = 0; i < 4; ++i) {
        int m = m0 + mt * 4 + i;
        float4 v0 = {acc[i][0], acc[i][1], acc[i][2], acc[i][3]};
        float4 v1 = {acc[i][4], acc[i][5], acc[i][6], acc[i][7]};
        ((float4*)h)[(size_t)m * (OUT_DIM / 4) + ot * 2 + 0] = v0;
        ((float4*)h)[(size_t)m * (OUT_DIM / 4) + ot * 2 + 1] = v1;
        float ps = 0.f, pd = 0.f;
#pragma unroll
        for (int j = 0; j < 8; ++j) {
            ps = fmaf(acc[i][j], as8[j], ps);
            pd = fmaf(acc[i][j], ad8[j], pd);
        }
        redS[mt * 4 + i][ot] = ps;
        redD[mt * 4 + i][ot] = pd;
    }
    __syncthreads();
    if (tid < 64) {
        float ss = 0.f, dd = 0.f;
#pragma unroll
        for (int t = 0; t < 16; ++t) { ss += redS[tid][t]; dd += redD[tid][t]; }
        src[m0 + tid] = ss;
        dstv[m0 + tid] = dd;
    }
}

// ---------------- Kernel R1: partial ranks (jj-chunked) ----------------
__global__ __launch_bounds__(256) void rankpart_kernel(
    const float* __restrict__ dstv, int* __restrict__ rpart)
{
    __shared__ float ld[256];
    int blk = blockIdx.x;
    int b  = blk >> 6;
    int jc = (blk >> 3) & 7;
    int kc = blk & 7;
    const float* db = dstv + b * NN;
    ld[threadIdx.x] = db[kc * 256 + threadIdx.x];
    __syncthreads();
    int j = jc * 256 + threadIdx.x;
    float myd = db[j];
    int base = kc * 256;
    int rank = 0;
    const float4* l4 = (const float4*)ld;
#pragma unroll 8
    for (int q = 0; q < 64; ++q) {
        float4 v = l4[q];
        int jj = base + q * 4;
        rank += (v.x < myd) || (v.x == myd && jj + 0 < j);
        rank += (v.y < myd) || (v.y == myd && jj + 1 < j);
        rank += (v.z < myd) || (v.z == myd && jj + 2 < j);
        rank += (v.w < myd) || (v.w == myd && jj + 3 < j);
    }
    rpart[((size_t)b * NN + j) * 8 + kc] = rank;
}

// ---------------- Kernel R2: combine partials, scatter + weights ----------------
__global__ __launch_bounds__(256) void rankcombine_kernel(
    const float* __restrict__ dstv, const int* __restrict__ mask,
    const int* __restrict__ rpart,
    float* __restrict__ sorted_d, int* __restrict__ sorted_idx,
    float* __restrict__ wpos, float* __restrict__ wneg)
{
    int j = blockIdx.x * 256 + threadIdx.x;
    int b = j >> 11;
    const int4* rp = (const int4*)(rpart + (size_t)j * 8);
    int4 r0 = rp[0], r1 = rp[1];
    int rank = r0.x + r0.y + r0.z + r0.w + r1.x + r1.y + r1.z + r1.w;
    float myd = dstv[j];
    int lj = j & (NN - 1);
    sorted_d[b * NN + rank]   = myd;
    sorted_idx[b * NN + rank] = lj;
    int mk = mask[j];
    wpos[b * NN + rank] = mk ? expf(myd) : 0.f;
    wneg[b * NN + rank] = mk ? expf(0.2f * myd) : 0.f;
}

// ---------------- Kernel D1: per-chunk sums ----------------
__global__ __launch_bounds__(128) void chunksum_kernel(
    const float* __restrict__ h, const int* __restrict__ sidx,
    const float* __restrict__ wpos, const float* __restrict__ wneg,
    float* __restrict__ cPos, float* __restrict__ cNeg,
    float* __restrict__ cPosW, float* __restrict__ cNegW)
{
    int b = blockIdx.x / NCHUNK;
    int c = blockIdx.x % NCHUNK;
    int o = threadIdx.x;
    int r0 = c * CHUNK;
    float ap = 0.f, an = 0.f, apw = 0.f, anw = 0.f;
    for (int r = 0; r < CHUNK; ++r) {
        int rr = b * NN + r0 + r;
        int jj = sidx[rr];
        float wp = wpos[rr], wn = wneg[rr];
        float hv = h[((size_t)b * NN + jj) * OUT_DIM + o];
        ap = fmaf(wp, hv, ap);
        an = fmaf(wn, hv, an);
        apw += wp; anw += wn;
    }
    int cidx = b * NCHUNK + c;
    cPos[(size_t)cidx * OUT_DIM + o] = ap;
    cNeg[(size_t)cidx * OUT_DIM + o] = an;
    if (o == 0) { cPosW[cidx] = apw; cNegW[cidx] = anw; }
}

// ---------------- Kernel D3': fused cross-chunk prefix + expand ----------------
__global__ __launch_bounds__(128) void scanwrite_kernel(
    const float* __restrict__ h, const int* __restrict__ sidx,
    const float* __restrict__ wpos, const float* __restrict__ wneg,
    const float* __restrict__ cPos, const float* __restrict__ cNeg,
    const float* __restrict__ cPosW, const float* __restrict__ cNegW,
    float* __restrict__ PreH, float* __restrict__ SufH,
    float* __restrict__ PreW, float* __restrict__ SufW)
{
    __shared__ float hs[CHUNK][OUT_DIM];   // 16 KB
    __shared__ float wn_s[CHUNK], wp_s[CHUNK];
    __shared__ int   si_s[CHUNK];
    int b = blockIdx.x / NCHUNK;
    int c = blockIdx.x % NCHUNK;
    int o = threadIdx.x;
    int r0 = c * CHUNK;
    size_t hb = (size_t)b * NN;
    size_t pb = (size_t)b * (NN + 1);

    if (o < CHUNK) {
        int rr = b * NN + r0 + o;
        si_s[o] = sidx[rr];
        wn_s[o] = wneg[rr];
        wp_s[o] = wpos[rr];
    }
    __syncthreads();
    // stage the 32 gathered h rows (each row 128 floats; 32 float4-lanes/row)
#pragma unroll
    for (int it = 0; it < 8; ++it) {
        int row = it * 4 + (o >> 5);
        int c4 = o & 31;
        float4 v = ((const float4*)h)[(hb + si_s[row]) * (OUT_DIM / 4) + c4];
        *(float4*)&hs[row][c4 * 4] = v;
    }

    // inline cross-chunk exclusive prefix (fwd over cNeg, bwd over cPos)
    float bn = 0.f, bp = 0.f;
    for (int cc = 0; cc < c; ++cc)
        bn += cNeg[(size_t)(b * NCHUNK + cc) * OUT_DIM + o];
    for (int cc = c + 1; cc < NCHUNK; ++cc)
        bp += cPos[(size_t)(b * NCHUNK + cc) * OUT_DIM + o];
    __syncthreads();

    // forward (exclusive prefix of wneg*h)
    float acc = bn;
#pragma unroll
    for (int r = 0; r < CHUNK; ++r) {
        PreH[(pb + r0 + r) * OUT_DIM + o] = acc;
        acc = fmaf(wn_s[r], hs[r][o], acc);
    }
    if (c == NCHUNK - 1) PreH[(pb + NN) * OUT_DIM + o] = acc;

    // backward (inclusive suffix of wpos*h)
    float accp = bp;
#pragma unroll
    for (int r = CHUNK - 1; r >= 0; --r) {
        accp = fmaf(wp_s[r], hs[r][o], accp);
        SufH[(pb + r0 + r) * OUT_DIM + o] = accp;
    }
    if (c == NCHUNK - 1) SufH[(pb + NN) * OUT_DIM + o] = 0.f;

    // scalar weight scans (two threads, one direction each)
    if (o == 0) {
        float a = 0.f;
        for (int cc = 0; cc < c; ++cc) a += cNegW[b * NCHUNK + cc];
        for (int r = 0; r < CHUNK; ++r) { PreW[pb + r0 + r] = a; a += wn_s[r]; }
        if (c == NCHUNK - 1) PreW[pb + NN] = a;
    }
    if (o == 1) {
        float a = 0.f;
        for (int cc = c + 1; cc < NCHUNK; ++cc) a += cPosW[b * NCHUNK + cc];
        for (int r = CHUNK - 1; r >= 0; --r) { a += wp_s[r]; SufW[pb + r0 + r] = a; }
        if (c == NCHUNK - 1) SufW[pb + NN] = 0.f;
    }
}

// ---------------- Kernel E': per-query combine, 64 queries/block ----------------
__global__ __launch_bounds__(256) void query_kernel(
    const float* __restrict__ src, const float* __restrict__ sorted_d,
    const float* __restrict__ PreH, const float* __restrict__ SufH,
    const float* __restrict__ PreW, const float* __restrict__ SufW,
    float* __restrict__ out)
{
    __shared__ float sd_s[NN];       // 8 KB
    __shared__ int   lo_s[64];
    __shared__ float pe_s[64], pn_s[64], sc_s[64];
    const int tid = threadIdx.x;
    const int q0 = blockIdx.x * 64;
    const int b  = blockIdx.x >> 5;          // 32 blocks per batch
    const size_t pb = (size_t)b * (NN + 1);

    // stage sorted_d for this batch
    const float4* sd4 = (const float4*)(sorted_d + b * NN);
#pragma unroll
    for (int it = 0; it < 2; ++it) {
        float4 v = sd4[it * 256 + tid];
        *(float4*)&sd_s[(it * 256 + tid) * 4] = v;
    }
    __syncthreads();

    if (tid < 64) {
        int q = q0 + tid;
        float s = src[q];
        float t = -s;
        int lo = 0, hi = NN;
        while (lo < hi) {
            int mid = (lo + hi) >> 1;
            if (sd_s[mid] > t) hi = mid; else lo = mid + 1;
        }
        float pe = expf(s), pn = expf(0.2f * s);
        float den = pe * SufW[pb + lo] + pn * PreW[pb + lo];
        lo_s[tid] = lo;
        pe_s[tid] = pe;
        pn_s[tid] = pn;
        sc_s[tid] = (den > 0.f) ? 1.f / den : 0.f;
    }
    __syncthreads();

    const int o  = tid & 127;
    const int qh = tid >> 7;   // 0 or 1
#pragma unroll 4
    for (int ps = 0; ps < 32; ++ps) {
        int ql = ps * 2 + qh;
        size_t base = pb + lo_s[ql];
        float num = pe_s[ql] * SufH[base * OUT_DIM + o] + pn_s[ql] * PreH[base * OUT_DIM + o];
        out[(size_t)(q0 + ql) * OUT_DIM + o] = num * sc_s[ql];
    }
}

// ---------------- launcher ----------------
extern "C" void kernel_launch(void* const* d_in, const int* in_sizes, int n_in,
                              void* d_out, int out_size, void* d_ws, size_t ws_size,
                              hipStream_t stream)
{
    const float* x     = (const float*)d_in[0];
    const int*   mask  = (const int*)d_in[1];
    const float* W     = (const float*)d_in[2];
    const float* a_src = (const float*)d_in[3];
    const float* a_dst = (const float*)d_in[4];
    float* out = (float*)d_out;
    float* ws  = (float*)d_ws;

    float* h        = ws + OFF_H;
    float* src      = ws + OFF_SRC;
    float* dstv     = ws + OFF_DST;
    float* sorted_d = ws + OFF_SD;
    int*   sidx     = (int*)(ws + OFF_SI);
    float* wpos     = ws + OFF_WP;
    float* wneg     = ws + OFF_WN;
    float* cPos     = ws + OFF_CP;
    float* cNeg     = ws + OFF_CN;
    float* cPosW    = ws + OFF_CPW;
    float* cNegW    = ws + OFF_CNW;
    float* PreH     = ws + OFF_PREH;
    float* SufH     = ws + OFF_SUFH;
    float* PreW     = ws + OFF_PREW;
    float* SufW     = ws + OFF_SUFW;
    int*   rpart    = (int*)(ws + OFF_RP);

    gat_gemm_kernel<<<M_TOT / 64, 256, 0, stream>>>(x, W, a_src, a_dst, h, src, dstv);
    rankpart_kernel<<<BB * 64, 256, 0, stream>>>(dstv, rpart);
    rankcombine_kernel<<<M_TOT / 256, 256, 0, stream>>>(dstv, mask, rpart, sorted_d, sidx, wpos, wneg);
    chunksum_kernel<<<BB * NCHUNK, 128, 0, stream>>>(h, sidx, wpos, wneg, cPos, cNeg, cPosW, cNegW);
    scanwrite_kernel<<<BB * NCHUNK, 128, 0, stream>>>(h, sidx, wpos, wneg, cPos, cNeg, cPosW, cNegW,
                                                      PreH, SufH, PreW, SufW);
    query_kernel<<<M_TOT / 64, 256, 0, stream>>>(src, sorted_d, PreH, SufH, PreW, SufW, out);
}